// Round 5
// baseline (389.876 us; speedup 1.0000x reference)
//
#include <hip/hip_runtime.h>

typedef unsigned int u32;
typedef __fp16 h2  __attribute__((ext_vector_type(2)));
typedef __fp16 v8h __attribute__((ext_vector_type(8)));
typedef float  f32x4 __attribute__((ext_vector_type(4)));

#define BB 4
#define HH 180
#define WWD 320
#define HW_ 57600            // H*W
#define TENSOR_ 14745600     // B*C*H*W

union U4 { float4 f; v8h h8; h2 h[4]; };
union U2 { float2 f; h2 h[2]; };

// ---- module-scope scratch ----
__device__ __align__(16) float g_gap[512];      // [side][b][c]
__device__ __align__(16) float g_bagg[512];     // [side][b][o]
__device__ __align__(16) float g_swn[128];      // [side][o] sum of rounded folded w1
__device__ __align__(16) float g_sb[128];       // [side][o] = sum(w1*nb) + p1b
__device__ __align__(16) float g_vb[128];       // [side][o] = p2b
__device__ __align__(16) h2 g_w1fH[4096];       // [side][o][m] LN-folded p1 (i-pairs)
__device__ __align__(16) h2 g_p2H[4096];        // [side][o][m] p2
__device__ __align__(16) h2 g_waggH[16384];     // [side][b][o][m] dyn conv W

// ---------------- kernel 1: global average pool -> g_gap
__global__ __launch_bounds__(256) void gap_kernel(const float* __restrict__ xl,
                                                  const float* __restrict__ xr) {
    int job = blockIdx.x;                 // side*256 + b*64 + c
    int side = job >> 8;
    int bc = job & 255;
    const float4* p = (const float4*)((side ? xr : xl) + (size_t)bc * HW_);
    float s = 0.f;
    for (int i = threadIdx.x; i < 14400; i += 256) {
        float4 v = p[i];
        s += v.x + v.y + v.z + v.w;
    }
    #pragma unroll
    for (int off = 32; off > 0; off >>= 1) s += __shfl_down(s, off, 64);
    __shared__ float red[4];
    int lane = threadIdx.x & 63, wv = threadIdx.x >> 6;
    if (lane == 0) red[wv] = s;
    __syncthreads();
    if (threadIdx.x == 0)
        g_gap[job] = (red[0] + red[1] + red[2] + red[3]) * (1.f / 57600.f);
}

// ---------------- kernel 2: expert mixture + fp16 row-major weight tables + bagg
__global__ __launch_bounds__(256) void prep_kernel(
    const float* __restrict__ nlw, const float* __restrict__ nlb,
    const float* __restrict__ nrw, const float* __restrict__ nrb,
    const float* __restrict__ lp1w, const float* __restrict__ rp1w,
    const float* __restrict__ lp2w, const float* __restrict__ rp2w,
    const float* __restrict__ lp1b, const float* __restrict__ rp1b,
    const float* __restrict__ lp2b, const float* __restrict__ rp2b,
    const float* __restrict__ lf1w, const float* __restrict__ lf1b,
    const float* __restrict__ lf2w, const float* __restrict__ lf2b,
    const float* __restrict__ lfbias,
    const float* __restrict__ rf1w, const float* __restrict__ rf1b,
    const float* __restrict__ rf2w, const float* __restrict__ rf2b,
    const float* __restrict__ rfbias,
    const float* __restrict__ lfW, const float* __restrict__ rfW)
{
    __shared__ float att[2][4][3];
    int t = threadIdx.x;
    if (t < 8) {
        int side = t >> 2, b = t & 3;
        const float* f1w = side ? rf1w : lf1w;
        const float* f1b = side ? rf1b : lf1b;
        const float* f2w = side ? rf2w : lf2w;
        const float* f2bv = side ? rf2b : lf2b;
        const float* g = g_gap + side*256 + b*64;
        float a1[3];
        #pragma unroll
        for (int k = 0; k < 3; k++) {
            float s = f1b[k];
            for (int c = 0; c < 64; c++) s += g[c] * f1w[k*64 + c];
            a1[k] = fmaxf(s, 0.f);
        }
        float a2[3];
        #pragma unroll
        for (int j = 0; j < 3; j++) {
            float s = f2bv[j];
            #pragma unroll
            for (int k = 0; k < 3; k++) s += a1[k] * f2w[j*3 + k];
            a2[j] = s;
        }
        float m = fmaxf(fmaxf(a2[0], a2[1]), a2[2]);
        float e0 = __expf(a2[0]-m), e1 = __expf(a2[1]-m), e2 = __expf(a2[2]-m);
        float inv = 1.f / (e0 + e1 + e2);
        att[side][b][0] = e0*inv; att[side][b][1] = e1*inv; att[side][b][2] = e2*inv;
    }
    __syncthreads();

    if (blockIdx.x < 16) {
        // wagg fp16 row-major [side][b][o][i-pairs m]
        int flat = blockIdx.x * 256 + t;     // 4096 jobs
        int row = flat >> 3, seg = flat & 7; // row = (side*4+b)*64 + o
        int side = row >> 8, bb = (row >> 6) & 3, o = row & 63;
        const float* Wp = side ? rfW : lfW;
        float a0 = att[side][bb][0], a1 = att[side][bb][1], a2 = att[side][bb][2];
        #pragma unroll
        for (int e = 0; e < 4; e++) {
            int m = seg*4 + e;
            int i0 = 2*m;
            float wi0 = a0*Wp[o*64+i0]   + a1*Wp[4096+o*64+i0]   + a2*Wp[8192+o*64+i0];
            float wi1 = a0*Wp[o*64+i0+1] + a1*Wp[4096+o*64+i0+1] + a2*Wp[8192+o*64+i0+1];
            g_waggH[row*32 + m] = __builtin_amdgcn_cvt_pkrtz(wi0, wi1);
        }
    } else {
        if (t < 128) {
            int side = t >> 6, o = t & 63;
            const float* w1 = side ? rp1w : lp1w;
            const float* w2 = side ? rp2w : lp2w;
            const float* nw = side ? nrw : nlw;
            const float* nb = side ? nrb : nlb;
            const float* b1 = side ? rp1b : lp1b;
            const float* b2 = side ? rp2b : lp2b;
            float s_wn = 0.f, s_b = 0.f;
            for (int m = 0; m < 32; m++) {
                float wf0 = w1[o*64 + 2*m],   wf1 = w1[o*64 + 2*m+1];
                h2 hw = __builtin_amdgcn_cvt_pkrtz(wf0 * nw[2*m], wf1 * nw[2*m+1]);
                g_w1fH[(side*64 + o)*32 + m] = hw;
                g_p2H [(side*64 + o)*32 + m] =
                    __builtin_amdgcn_cvt_pkrtz(w2[o*64+2*m], w2[o*64+2*m+1]);
                s_wn += (float)hw.x + (float)hw.y;   // consistent with rounded weights
                s_b  += wf0*nb[2*m] + wf1*nb[2*m+1];
            }
            g_swn[side*64 + o] = s_wn;
            g_sb[side*64 + o]  = s_b + b1[o];
            g_vb[side*64 + o]  = b2[o];
        }
        for (int idx = t; idx < 512; idx += 256) {
            int side = idx >> 8, r = idx & 255, b = r >> 6, o = r & 63;
            const float* bp = side ? rfbias : lfbias;
            g_bagg[idx] = att[side][b][0]*bp[o]
                        + att[side][b][1]*bp[64+o]
                        + att[side][b][2]*bp[128+o];
        }
    }
}

// ---------------- kernel 3: fused, MFMA-based, LDS-access-optimized.
// Conventions (validated R4): operands stored [free dim][K] fp16; A- and B-frags
// use identical k-addressing (k = kt*32 + (lane>>4)*8 + j); D: col = lane&15 = N,
// row = (lane>>4)*4 + reg = M.
// smA region: xA [side][px48][m36 h2] during P0-P2; Vb [side][o64][v56 fp16] after.
__global__ __launch_bounds__(256, 4) void main_kernel(
    const float* __restrict__ xl_g, const float* __restrict__ xr_g,
    const float* __restrict__ beta, const float* __restrict__ gamma,
    float* __restrict__ out)
{
    __shared__ __align__(16) unsigned char smA[14368];  // xA (13824) / Vb (14336) + slack
    __shared__ __align__(16) __fp16 qA[2][48][72];      // Q^T then F^T [px][o]
    __shared__ float attn[4][10][10];
    __shared__ __align__(16) __fp16 AH[2][4][16][40];   // softmax rows, 40-pad (2-way banks)
    __shared__ float muS[2][48], rsS[2][48];

    h2*     xA = (h2*)smA;          // idx (side*48+px)*36 + m
    __fp16* Vb = (__fp16*)smA;      // idx (side*64+o)*56 + v

    int t = threadIdx.x;
    int wv = t >> 6, lane = t & 63;
    int g16 = lane >> 4, i16 = lane & 15;
    int bid = blockIdx.x;
    int b  = bid / (HH*8);
    int r0 = bid % (HH*8);
    int h  = r0 / 8;
    int g  = r0 % 8;
    int w0 = g * 40;

    f32x4 z4; z4[0]=0.f; z4[1]=0.f; z4[2]=0.f; z4[3]=0.f;

    // ---- P0: stage x -> xA fp16; zero px pad rows 40..47 ----
    for (int idx = t; idx < 1216; idx += 256) {
        if (idx < 640) {
            int tensor = idx / 320;
            int r2 = idx - tensor*320;
            int m = r2 / 10, seg = r2 - m*10;
            const float* src = (tensor ? xr_g : xl_g)
                             + (((size_t)(b*64 + 2*m)*HH + h)*WWD + w0 + seg*4);
            float4 a = *(const float4*)(src);
            float4 c = *(const float4*)(src + HW_);    // odd channel, same pixels
            xA[(tensor*48 + seg*4+0)*36 + m] = __builtin_amdgcn_cvt_pkrtz(a.x, c.x);
            xA[(tensor*48 + seg*4+1)*36 + m] = __builtin_amdgcn_cvt_pkrtz(a.y, c.y);
            xA[(tensor*48 + seg*4+2)*36 + m] = __builtin_amdgcn_cvt_pkrtz(a.z, c.z);
            xA[(tensor*48 + seg*4+3)*36 + m] = __builtin_amdgcn_cvt_pkrtz(a.w, c.w);
        } else {
            int z = idx - 640;
            int side = z / 288, rr = z - side*288;
            int row = 40 + rr/36, col = rr - (rr/36)*36;
            h2 hz; hz.x = (__fp16)0.f; hz.y = (__fp16)0.f;
            xA[(side*48 + row)*36 + col] = hz;
        }
    }
    __syncthreads();

    // ---- P1: LN stats per px row ----
    if (t < 96) {
        int side = t / 48, u = t - side*48;
        const h2* row = xA + (side*48 + u)*36;
        h2 one2; one2.x = (__fp16)1.f; one2.y = (__fp16)1.f;
        float s = 0.f, s2 = 0.f;
        #pragma unroll
        for (int q = 0; q < 8; q++) {
            U4 v; v.f = *(const float4*)(row + q*4);
            #pragma unroll
            for (int e = 0; e < 4; e++) {
                s  = __builtin_amdgcn_fdot2(v.h[e], one2,   s,  false);
                s2 = __builtin_amdgcn_fdot2(v.h[e], v.h[e], s2, false);
            }
        }
        float mu = s * (1.f/64.f);
        float var = fmaxf(s2 * (1.f/64.f) - mu*mu, 0.f);
        muS[side][u] = mu;
        rsS[side][u] = rsqrtf(var + 1e-6f);
    }
    __syncthreads();

    // ---- P2: projections. waves 0/1: Q (A=w1f, B=x). waves 2/3: V SWAPPED (A=x, B=p2)
    //      so V-D comes out as [o][px-contig] -> vectorized Vb writes. ----
    int side2 = wv & 1;
    {
        f32x4 acc[12];
        #pragma unroll
        for (int i = 0; i < 12; i++) acc[i] = z4;

        __builtin_amdgcn_s_setprio(1);
        if (wv < 2) {
            const h2* wTab = g_w1fH + side2*2048;
            #pragma unroll
            for (int kt = 0; kt < 2; kt++) {
                U4 bf[3];
                #pragma unroll
                for (int nt = 0; nt < 3; nt++)
                    bf[nt].f = *(const float4*)&xA[(side2*48 + nt*16 + i16)*36 + kt*16 + g16*4];
                #pragma unroll
                for (int mt = 0; mt < 4; mt++) {
                    U4 af; af.f = *(const float4*)(wTab + (mt*16 + i16)*32 + kt*16 + g16*4);
                    #pragma unroll
                    for (int nt = 0; nt < 3; nt++)
                        acc[mt*3+nt] = __builtin_amdgcn_mfma_f32_16x16x32_f16(
                            af.h8, bf[nt].h8, acc[mt*3+nt], 0, 0, 0);
                }
            }
        } else {
            const h2* wTab = g_p2H + side2*2048;
            #pragma unroll
            for (int kt = 0; kt < 2; kt++) {
                U4 af[3];
                #pragma unroll
                for (int mp = 0; mp < 3; mp++)
                    af[mp].f = *(const float4*)&xA[(side2*48 + mp*16 + i16)*36 + kt*16 + g16*4];
                #pragma unroll
                for (int no = 0; no < 4; no++) {
                    U4 bf; bf.f = *(const float4*)(wTab + (no*16 + i16)*32 + kt*16 + g16*4);
                    #pragma unroll
                    for (int mp = 0; mp < 3; mp++)
                        acc[no*3+mp] = __builtin_amdgcn_mfma_f32_16x16x32_f16(
                            af[mp].h8, bf.h8, acc[no*3+mp], 0, 0, 0);
                }
            }
        }
        __builtin_amdgcn_s_setprio(0);
        __syncthreads();   // xA raw-x fully consumed; Vb overlay may start

        if (wv < 2) {      // Q epilogue: LN fold -> qA[side][u][c]
            #pragma unroll
            for (int nt = 0; nt < 3; nt++) {
                int u = nt*16 + i16;
                float mu = muS[side2][u], rs = rsS[side2][u];
                #pragma unroll
                for (int mt = 0; mt < 4; mt++) {
                    float4 swl = *(const float4*)&g_swn[side2*64 + mt*16 + g16*4];
                    float4 sbl = *(const float4*)&g_sb [side2*64 + mt*16 + g16*4];
                    f32x4 a = acc[mt*3+nt];
                    float e0 = rs*(a[0] - mu*swl.x) + sbl.x;
                    float e1 = rs*(a[1] - mu*swl.y) + sbl.y;
                    float e2 = rs*(a[2] - mu*swl.z) + sbl.z;
                    float e3 = rs*(a[3] - mu*swl.w) + sbl.w;
                    h2* dst = (h2*)&qA[side2][u][mt*16 + g16*4];
                    dst[0] = __builtin_amdgcn_cvt_pkrtz(e0, e1);
                    dst[1] = __builtin_amdgcn_cvt_pkrtz(e2, e3);
                }
            }
        } else {           // V epilogue: +bias -> Vb[side][o][px], b64 writes
            #pragma unroll
            for (int no = 0; no < 4; no++) {
                int o = no*16 + i16;
                float vbias = g_vb[side2*64 + o];
                __fp16* row = Vb + (side2*64 + o)*56;
                #pragma unroll
                for (int mp = 0; mp < 3; mp++) {
                    f32x4 a = acc[no*3+mp];
                    U2 p;
                    p.h[0] = __builtin_amdgcn_cvt_pkrtz(a[0]+vbias, a[1]+vbias);
                    p.h[1] = __builtin_amdgcn_cvt_pkrtz(a[2]+vbias, a[3]+vbias);
                    *(float2*)&row[mp*16 + g16*4] = p.f;
                }
            }
            {   // zero row pads v=48..55 (one o per lane) + region slack
                __fp16* row = Vb + (side2*64 + lane)*56;
                float2 z2 = make_float2(0.f, 0.f);
                *(float2*)&row[48] = z2;
                *(float2*)&row[52] = z2;
                if (wv == 2 && lane < 8) ((float*)(smA + 14336))[lane] = 0.f;
            }
        }
    }
    __syncthreads();

    // ---- P3: scores S = Ql^T Qr per 10-chunk; wave = chunk ----
    {
        const __fp16* ra = &qA[0][wv*10 + i16][0];
        const __fp16* rb = &qA[1][wv*10 + i16][0];
        f32x4 s = z4;
        #pragma unroll
        for (int kt = 0; kt < 2; kt++) {
            U4 af, bf;
            af.f = *(const float4*)(ra + kt*32 + g16*8);
            bf.f = *(const float4*)(rb + kt*32 + g16*8);
            s = __builtin_amdgcn_mfma_f32_16x16x32_f16(af.h8, bf.h8, s, 0, 0, 0);
        }
        #pragma unroll
        for (int reg = 0; reg < 4; reg++) {
            int r = g16*4 + reg;
            if (r < 10 && i16 < 10) attn[wv][r][i16] = s[reg] * 0.125f;
        }
    }
    __syncthreads();

    // ---- softmax -> AH fp16 rows (k-slots 0..31 populated, 10..31 zero) ----
    if (t < 40) {                      // over v -> AH[0][ch][u][v]
        int k = t / 10, uu = t - (t/10)*10;
        float m = attn[k][uu][0];
        #pragma unroll
        for (int v2 = 1; v2 < 10; v2++) m = fmaxf(m, attn[k][uu][v2]);
        float e[10]; float ssum = 0.f;
        #pragma unroll
        for (int v2 = 0; v2 < 10; v2++) { e[v2] = __expf(attn[k][uu][v2] - m); ssum += e[v2]; }
        float inv = 1.f / ssum;
        h2 hz; hz.x = (__fp16)0.f; hz.y = (__fp16)0.f;
        U4 r0_, r1_;
        r0_.h[0] = __builtin_amdgcn_cvt_pkrtz(e[0]*inv, e[1]*inv);
        r0_.h[1] = __builtin_amdgcn_cvt_pkrtz(e[2]*inv, e[3]*inv);
        r0_.h[2] = __builtin_amdgcn_cvt_pkrtz(e[4]*inv, e[5]*inv);
        r0_.h[3] = __builtin_amdgcn_cvt_pkrtz(e[6]*inv, e[7]*inv);
        r1_.h[0] = __builtin_amdgcn_cvt_pkrtz(e[8]*inv, e[9]*inv);
        r1_.h[1] = hz; r1_.h[2] = hz; r1_.h[3] = hz;
        float4 zf = make_float4(0.f,0.f,0.f,0.f);
        float4* dst = (float4*)&AH[0][k][uu][0];
        dst[0] = r0_.f; dst[1] = r1_.f; dst[2] = zf; dst[3] = zf;
    } else if (t >= 64 && t < 104) {   // over u -> AH[1][ch][v][u]
        int t2 = t - 64;
        int k = t2 / 10, vv = t2 - (t2/10)*10;
        float m = attn[k][0][vv];
        #pragma unroll
        for (int u2 = 1; u2 < 10; u2++) m = fmaxf(m, attn[k][u2][vv]);
        float e[10]; float ssum = 0.f;
        #pragma unroll
        for (int u2 = 0; u2 < 10; u2++) { e[u2] = __expf(attn[k][u2][vv] - m); ssum += e[u2]; }
        float inv = 1.f / ssum;
        h2 hz; hz.x = (__fp16)0.f; hz.y = (__fp16)0.f;
        U4 r0_, r1_;
        r0_.h[0] = __builtin_amdgcn_cvt_pkrtz(e[0]*inv, e[1]*inv);
        r0_.h[1] = __builtin_amdgcn_cvt_pkrtz(e[2]*inv, e[3]*inv);
        r0_.h[2] = __builtin_amdgcn_cvt_pkrtz(e[4]*inv, e[5]*inv);
        r0_.h[3] = __builtin_amdgcn_cvt_pkrtz(e[6]*inv, e[7]*inv);
        r1_.h[0] = __builtin_amdgcn_cvt_pkrtz(e[8]*inv, e[9]*inv);
        r1_.h[1] = hz; r1_.h[2] = hz; r1_.h[3] = hz;
        float4 zf = make_float4(0.f,0.f,0.f,0.f);
        float4* dst = (float4*)&AH[1][k][vv][0];
        dst[0] = r0_.f; dst[1] = r1_.f; dst[2] = zf; dst[3] = zf;
    }
    __syncthreads();

    // ---- residual prefetch (for P5; hides HBM latency under P4) ----
    int side5 = wv >> 1, mth = wv & 1;
    const float* xsrc = side5 ? xr_g : xl_g;
    float res[2][3][4];
    #pragma unroll
    for (int m2 = 0; m2 < 2; m2++)
        #pragma unroll
        for (int nt = 0; nt < 3; nt++) {
            int px = nt*16 + i16;
            #pragma unroll
            for (int reg = 0; reg < 4; reg++) {
                int o = mth*32 + m2*16 + g16*4 + reg;
                res[m2][nt][reg] = (px < 40)
                    ? xsrc[(size_t)(b*64+o)*HW_ + (size_t)h*WWD + w0 + px] : 0.f;
            }
        }

    // ---- P4: F = V x A^T via MFMA. A-op = Vb rows o (b32 loads), B-op = AH rows
    //      (b128). D: row = o, col = u/v px -> b64 write of 4 consecutive o. ----
    {
        int dir = wv >> 1, oh = wv & 1, vside = dir ^ 1;
        const float* scp = dir ? gamma : beta;
        #pragma unroll
        for (int ch = 0; ch < 4; ch++) {
            U4 bf; bf.f = *(const float4*)&AH[dir][ch][i16][g16*8];
            #pragma unroll
            for (int m2 = 0; m2 < 2; m2++) {
                int mt = oh*2 + m2;
                const __fp16* vrow = Vb + (vside*64 + mt*16 + i16)*56 + ch*10 + g16*8;
                U4 af;
                af.h[0] = *(const h2*)&vrow[0];
                af.h[1] = *(const h2*)&vrow[2];
                af.h[2] = *(const h2*)&vrow[4];
                af.h[3] = *(const h2*)&vrow[6];
                f32x4 d = __builtin_amdgcn_mfma_f32_16x16x32_f16(af.h8, bf.h8, z4, 0, 0, 0);
                if (i16 < 10) {
                    int px = ch*10 + i16;
                    int o0 = mt*16 + g16*4;
                    float4 sc = *(const float4*)&scp[o0];
                    U2 p;
                    p.h[0] = __builtin_amdgcn_cvt_pkrtz(d[0]*sc.x, d[1]*sc.y);
                    p.h[1] = __builtin_amdgcn_cvt_pkrtz(d[2]*sc.z, d[3]*sc.w);
                    *(float2*)&qA[dir][px][o0] = p.f;
                }
            }
        }
    }
    __syncthreads();

    // ---- P5: dynamic conv via MFMA + bagg + residual; wave = (side, o-half) ----
    {
        const h2* wag = g_waggH + (size_t)((side5*4 + b)*64 + mth*32)*32;
        f32x4 acc[2][3];
        #pragma unroll
        for (int m2 = 0; m2 < 2; m2++)
            #pragma unroll
            for (int nt = 0; nt < 3; nt++) acc[m2][nt] = z4;

        __builtin_amdgcn_s_setprio(1);
        #pragma unroll
        for (int kt = 0; kt < 2; kt++) {
            U4 bf[3];
            #pragma unroll
            for (int nt = 0; nt < 3; nt++)
                bf[nt].f = *(const float4*)(&qA[side5][nt*16 + i16][kt*32 + g16*8]);
            #pragma unroll
            for (int m2 = 0; m2 < 2; m2++) {
                U4 af; af.f = *(const float4*)(wag + (m2*16 + i16)*32 + kt*16 + g16*4);
                #pragma unroll
                for (int nt = 0; nt < 3; nt++)
                    acc[m2][nt] = __builtin_amdgcn_mfma_f32_16x16x32_f16(
                        af.h8, bf[nt].h8, acc[m2][nt], 0, 0, 0);
            }
        }
        __builtin_amdgcn_s_setprio(0);

        #pragma unroll
        for (int m2 = 0; m2 < 2; m2++) {
            float4 bg = *(const float4*)&g_bagg[side5*256 + b*64 + mth*32 + m2*16 + g16*4];
            float bga[4] = {bg.x, bg.y, bg.z, bg.w};
            #pragma unroll
            for (int nt = 0; nt < 3; nt++) {
                int px = nt*16 + i16;
                if (px < 40) {
                    #pragma unroll
                    for (int reg = 0; reg < 4; reg++) {
                        int o = mth*32 + m2*16 + g16*4 + reg;
                        out[(size_t)side5*TENSOR_ + (size_t)(b*64+o)*HW_ + (size_t)h*WWD + w0 + px]
                            = acc[m2][nt][reg] + bga[reg] + res[m2][nt][reg];
                    }
                }
            }
        }
    }
}

extern "C" void kernel_launch(void* const* d_in, const int* in_sizes, int n_in,
                              void* d_out, int out_size, void* d_ws, size_t ws_size,
                              hipStream_t stream) {
    (void)in_sizes; (void)n_in; (void)out_size; (void)d_ws; (void)ws_size;
    const float* x_l = (const float*)d_in[0];
    const float* x_r = (const float*)d_in[1];

    gap_kernel<<<512, 256, 0, stream>>>(x_l, x_r);
    prep_kernel<<<17, 256, 0, stream>>>(
        (const float*)d_in[2],  (const float*)d_in[3],
        (const float*)d_in[4],  (const float*)d_in[5],
        (const float*)d_in[6],  (const float*)d_in[8],
        (const float*)d_in[10], (const float*)d_in[12],
        (const float*)d_in[7],  (const float*)d_in[9],
        (const float*)d_in[11], (const float*)d_in[13],
        (const float*)d_in[16], (const float*)d_in[17],
        (const float*)d_in[18], (const float*)d_in[19], (const float*)d_in[21],
        (const float*)d_in[22], (const float*)d_in[23],
        (const float*)d_in[24], (const float*)d_in[25], (const float*)d_in[27],
        (const float*)d_in[20], (const float*)d_in[26]);
    main_kernel<<<BB*HH*8, 256, 0, stream>>>(x_l, x_r,
        (const float*)d_in[14], (const float*)d_in[15],
        (float*)d_out);
}